// Round 3
// baseline (514.823 us; speedup 1.0000x reference)
//
#include <hip/hip_runtime.h>
#include <cstdint>
#include <cstddef>

// MI355X / gfx950. bf16 MFMA implementation of ConditionalCrossAttention.
// score = (qc+qp)|(qc+qp+qs)  dot  kc|kp   (algebraic refold of the concat heads)
// ws layout: K64[128][4096][64] bf16 | V32[128][4096][32] bf16 |
//            Q64[128][320][64] bf16  | Obf[16][300][256] bf16 | Wbf[3][256][256] bf16 |
//            Opart[128][4][320][32] bf16 | Mpart[128][4][320] f32 | Lpart[...] f32

typedef float  f4  __attribute__((ext_vector_type(4)));
typedef __bf16 b8v __attribute__((ext_vector_type(8)));

#define MFMA_BF16(a, b, c) __builtin_amdgcn_mfma_f32_16x16x32_bf16((a), (b), (c), 0, 0, 0)

#define GLD_LDS16(gp, lp)                                             \
  __builtin_amdgcn_global_load_lds(                                   \
      (const __attribute__((address_space(1))) void*)(gp),            \
      (__attribute__((address_space(3))) void*)(lp), 16, 0, 0)

// ---------------------------------------------------------------------------
// Prepass: convert key-side weights fp32 -> bf16 (W_kc, W_kp, W_v -> Wbf[3][256*256])
__global__ __launch_bounds__(256) void convert_w(
    const float* __restrict__ W0, const float* __restrict__ W1,
    const float* __restrict__ W2, __bf16* __restrict__ Wbf)
{
  int i = blockIdx.x * 256 + threadIdx.x;      // 0 .. 49151
  int base = i * 4;                            // elem index, 4 per thread
  int m = base >> 16;                          // which matrix
  int off = base & 65535;
  const float* W = (m == 0) ? W0 : (m == 1) ? W1 : W2;
  float4 v = *(const float4*)(W + off);
  __bf16 o[4];
  o[0] = (__bf16)v.x; o[1] = (__bf16)v.y; o[2] = (__bf16)v.z; o[3] = (__bf16)v.w;
  *(uint2*)(Wbf + (size_t)m * 65536 + off) = *(uint2*)o;
}

// ---------------------------------------------------------------------------
// Kernel A v2: key-side linears, m97-style (unchanged from R2).
__global__ __launch_bounds__(256, 2) void key_side_gemm(
    const float* __restrict__ key, const float* __restrict__ key_pos,
    const float* __restrict__ value, const __bf16* __restrict__ Wbf,
    const float* __restrict__ b_kc, const float* __restrict__ b_kp,
    const float* __restrict__ b_v,
    __bf16* __restrict__ K64, __bf16* __restrict__ V32)
{
  __shared__ char smem[65536];   // 2 x 32KB W dbuf; reused as 64KB output tile
  const int tid  = threadIdx.x;
  const int wave = tid >> 6, lane = tid & 63;
  const int lrow = lane & 15, quad = lane >> 4;
  const int p  = blockIdx.y;
  const int r0 = blockIdx.x * 128;
  const int rowbase = (wave & 1) * 64;     // 2x2 wave grid: 64 rows x 128 cols each
  const int colbase = (wave >> 1) * 128;

  const float* __restrict__ X = (p == 0) ? key : (p == 1) ? key_pos : value;
  const __bf16* __restrict__ Wb = Wbf + (size_t)p * 65536;
  const float* __restrict__ bias = (p == 0) ? b_kc : (p == 1) ? b_kp : b_v;

  auto stageW = [&](int buf, int kc) {
#pragma unroll
    for (int it = 0; it < 8; ++it) {
      int slot = it * 256 + tid;            // 2048 granules of 16B
      int wr = slot >> 3, gp = slot & 7;
      int g  = gp ^ (wr & 7);
      GLD_LDS16(Wb + (size_t)wr * 256 + kc + g * 8, smem + buf * 32768 + slot * 16);
    }
  };
  auto readB = [&](int buf, int ct, int kk4) -> b8v {   // kk4 = kk/8 (0 or 4)
    int wr = colbase + ct * 16 + lrow;
    int g  = (kk4 + quad) ^ (wr & 7);
    return *(const b8v*)(smem + buf * 32768 + wr * 128 + g * 16);
  };
  auto loadA = [&](float4* x0, float4* x1, int kc) {
#pragma unroll
    for (int rt = 0; rt < 4; ++rt) {
      const float* xp = X + (size_t)(r0 + rowbase + rt * 16 + lrow) * 256 + kc + quad * 8;
      x0[rt] = *(const float4*)xp;
      x1[rt] = *(const float4*)(xp + 4);
    }
  };
  auto mk = [&](float4 x0, float4 x1) -> b8v {
    b8v t;
    t[0] = (__bf16)x0.x; t[1] = (__bf16)x0.y; t[2] = (__bf16)x0.z; t[3] = (__bf16)x0.w;
    t[4] = (__bf16)x1.x; t[5] = (__bf16)x1.y; t[6] = (__bf16)x1.z; t[7] = (__bf16)x1.w;
    return t;
  };

  f4 acc[4][8];
#pragma unroll
  for (int i = 0; i < 4; ++i)
#pragma unroll
    for (int j = 0; j < 8; ++j) acc[i][j] = f4{0.f, 0.f, 0.f, 0.f};

  float4 c0[4], c1[4], d0[4], d1[4];
  loadA(c0, c1, 0);          // A for s=0, kk=0
  stageW(0, 0);
  __syncthreads();           // drains vmcnt(0): buf0 + c ready

  for (int s = 0; s < 4; ++s) {
    const int kc0 = s * 64, buf = s & 1;
    loadA(d0, d1, kc0 + 32);            // A for kk=32 (issued first: oldest in vmcnt)
    if (s < 3) stageW(buf ^ 1, kc0 + 64);

    b8v a[4];
#pragma unroll
    for (int rt = 0; rt < 4; ++rt) a[rt] = mk(c0[rt], c1[rt]);
#pragma unroll
    for (int ct = 0; ct < 8; ++ct) {
      b8v bfr = readB(buf, ct, 0);
#pragma unroll
      for (int rt = 0; rt < 4; ++rt) acc[rt][ct] = MFMA_BF16(a[rt], bfr, acc[rt][ct]);
    }

    if (s < 3) loadA(c0, c1, kc0 + 64);

#pragma unroll
    for (int rt = 0; rt < 4; ++rt) a[rt] = mk(d0[rt], d1[rt]);
#pragma unroll
    for (int ct = 0; ct < 8; ++ct) {
      b8v bfr = readB(buf, ct, 4);
#pragma unroll
      for (int rt = 0; rt < 4; ++rt) acc[rt][ct] = MFMA_BF16(a[rt], bfr, acc[rt][ct]);
    }
    __syncthreads();
  }

  // epilogue: acc -> LDS [128][256] bf16 -> coalesced 64B-line stores
  __bf16* Os = (__bf16*)smem;
#pragma unroll
  for (int ct = 0; ct < 8; ++ct) {
    int col = colbase + ct * 16 + lrow;
    float bv = bias[col];
#pragma unroll
    for (int rt = 0; rt < 4; ++rt)
#pragma unroll
      for (int r = 0; r < 4; ++r) {
        int row = rowbase + rt * 16 + quad * 4 + r;
        Os[row * 256 + col] = (__bf16)(acc[rt][ct][r] + bv);
      }
  }
  __syncthreads();
#pragma unroll
  for (int it = 0; it < 16; ++it) {
    int chunk = it * 64 + wave * 16 + (lane & 15);
    int q = lane >> 4;
    int row = chunk >> 3, h = chunk & 7;
    int R = r0 + row, l = R >> 4, bb = R & 15;
    uint4 v = *(const uint4*)(Os + chunk * 32 + q * 8);
    __bf16* dst = (p == 2) ? (V32 + ((size_t)(bb * 8 + h) * 4096 + l) * 32)
                           : (K64 + ((size_t)(bb * 8 + h) * 4096 + l) * 64 + p * 32);
    *(uint4*)(dst + q * 8) = v;
  }
}

// ---------------------------------------------------------------------------
// Kernel B: query-side (unchanged from R2).
__global__ __launch_bounds__(256) void query_side_gemm(
    const float* __restrict__ query, const float* __restrict__ query_pos,
    const float* __restrict__ query_sine,
    const float* __restrict__ W_qc, const float* __restrict__ b_qc,
    const float* __restrict__ W_qp, const float* __restrict__ b_qp,
    const float* __restrict__ W_qs, const float* __restrict__ b_qs,
    __bf16* __restrict__ Q64)
{
  __shared__ __bf16 Ws[256][72];
  const int tid  = threadIdx.x;
  const int wave = tid >> 6, lane = tid & 63;
  const int lrow = lane & 15, quad = lane >> 4;
  const int r0 = blockIdx.x * 64;

  f4 acc[16];
#pragma unroll
  for (int i = 0; i < 16; ++i) acc[i] = f4{0.f, 0.f, 0.f, 0.f};

  for (int kc = 0; kc < 768; kc += 64) {
    const float* X; const float* W;
    if (kc < 256)      { X = query;      W = W_qc; }
    else if (kc < 512) { X = query_pos;  W = W_qp; }
    else               { X = query_sine; W = W_qs; }
    const int ko = kc & 255;
#pragma unroll
    for (int it = 0; it < 16; ++it) {
      int idx = it * 256 + tid;
      int row = idx >> 4, c4 = idx & 15;
      float4 w = *(const float4*)(W + (size_t)row * 256 + ko + c4 * 4);
      __bf16* dp = &Ws[row][c4 * 4];
      dp[0] = (__bf16)w.x; dp[1] = (__bf16)w.y; dp[2] = (__bf16)w.z; dp[3] = (__bf16)w.w;
    }
    __syncthreads();
#pragma unroll
    for (int kk = 0; kk < 64; kk += 32) {
      const float* xp = X + (size_t)(r0 + wave * 16 + lrow) * 256 + ko + kk + quad * 8;
      float4 x0 = *(const float4*)xp;
      float4 x1 = *(const float4*)(xp + 4);
      b8v a;
      a[0] = (__bf16)x0.x; a[1] = (__bf16)x0.y; a[2] = (__bf16)x0.z; a[3] = (__bf16)x0.w;
      a[4] = (__bf16)x1.x; a[5] = (__bf16)x1.y; a[6] = (__bf16)x1.z; a[7] = (__bf16)x1.w;
#pragma unroll
      for (int ct = 0; ct < 16; ++ct) {
        b8v bf = *(const b8v*)&Ws[ct * 16 + lrow][kk + quad * 8];
        acc[ct] = MFMA_BF16(a, bf, acc[ct]);
      }
    }
    __syncthreads();
    if (kc == 448) {  // phase 1 (qc+qp) complete -> write half 0
#pragma unroll
      for (int ct = 0; ct < 16; ++ct) {
        int col = ct * 16 + lrow;
        float bsum = b_qc[col] + b_qp[col];
        int h = col >> 5, d = col & 31;
#pragma unroll
        for (int r = 0; r < 4; ++r) {
          int row = r0 + wave * 16 + quad * 4 + r;
          int n = row >> 4, bb = row & 15;
          Q64[((size_t)(bb * 8 + h) * 320 + n) * 64 + d] = (__bf16)((acc[ct][r] + bsum) * 0.125f);
        }
      }
    }
  }
#pragma unroll
  for (int ct = 0; ct < 16; ++ct) {
    int col = ct * 16 + lrow;
    float bsum = b_qc[col] + b_qp[col] + b_qs[col];
    int h = col >> 5, d = col & 31;
#pragma unroll
    for (int r = 0; r < 4; ++r) {
      int row = r0 + wave * 16 + quad * 4 + r;
      int n = row >> 4, bb = row & 15;
      Q64[((size_t)(bb * 8 + h) * 320 + n) * 64 + 32 + d] = (__bf16)((acc[ct][r] + bsum) * 0.125f);
    }
  }
}

// ---------------------------------------------------------------------------
// Kernel C v2: flash attention, L-split. Grid (4 L-splits, 128 bh); each block
// processes ALL 320 q-rows (5 tiles/wave) over its 1024-L range in chunks of 128.
// K/V read exactly once from HBM. K/V register-prefetched one chunk ahead
// (VGPR pipeline; loads in flight across the ~2000-cyc compute phase).
// LDS: Ks granule-xor-swizzled (uniform banking for b128 read+write),
// Vt staged via paired ds_write_b32 (pi(l), pi(l+16) adjacent), Ps per-wave
// private (no barrier on the P round-trip).
// Outputs: per-split normalized O (bf16) + per-row m,l (f32); combined later.
__global__ __launch_bounds__(256, 2) void attn_part(
    const __bf16* __restrict__ Q64, const __bf16* __restrict__ K64,
    const __bf16* __restrict__ V32,
    __bf16* __restrict__ Opart, float* __restrict__ Mpart, float* __restrict__ Lpart)
{
  __shared__ __bf16 Ks[128 * 64];     // swizzled 16B granules, no pad needed
  __shared__ __bf16 Vt[32][136];      // [d][pi(l)]
  __shared__ __bf16 Ps[4][16][136];   // per-wave private [q][pi(l)]
  const int tid  = threadIdx.x;
  const int wave = tid >> 6, lane = tid & 63;
  const int lrow = lane & 15, quad = lane >> 4;
  const int ls = blockIdx.x, bh = blockIdx.y;
  const int l0base = ls * 1024;

  const __bf16* Kb = K64 + (size_t)bh * 4096 * 64;
  const __bf16* Vb = V32 + (size_t)bh * 4096 * 32;

  // Q fragments: 5 tiles of 16 rows per wave (rows wave*80 + t*16 + ...)
  b8v qa0[5], qa1[5];
#pragma unroll
  for (int t = 0; t < 5; ++t) {
    const __bf16* Qb = Q64 + ((size_t)bh * 320 + wave * 80 + t * 16 + lrow) * 64;
    qa0[t] = *(const b8v*)(Qb + quad * 8);
    qa1[t] = *(const b8v*)(Qb + 32 + quad * 8);
  }

  // V staging map: thread handles rows (vr, vr+16), octet vs; pi(vr+16)=pi(vr)+1
  const int vk = tid >> 4, vpg = (tid >> 2) & 3, vs = tid & 3;
  const int vr  = vpg * 32 + vk;
  const int vpi = vk * 8 + 2 * vpg;        // pi(vr)

  auto loadKV = [&](uint4* kr, uint4* vv, int c) {
    int l0 = l0base + c * 128;
#pragma unroll
    for (int it = 0; it < 4; ++it) {
      int slot = it * 256 + tid, row = slot >> 3, gs = slot & 7;
      int g = gs ^ (row & 7);
      kr[it] = *(const uint4*)(Kb + (size_t)(l0 + row) * 64 + g * 8);
    }
    vv[0] = *(const uint4*)(Vb + (size_t)(l0 + vr) * 32 + vs * 8);
    vv[1] = *(const uint4*)(Vb + (size_t)(l0 + vr + 16) * 32 + vs * 8);
  };
  auto stage = [&](const uint4* kr, const uint4* vv) {
#pragma unroll
    for (int it = 0; it < 4; ++it) {
      int slot = it * 256 + tid;
      *(uint4*)((char*)Ks + slot * 16) = kr[it];
    }
    __bf16 a[8], b[8];
    *(uint4*)a = vv[0]; *(uint4*)b = vv[1];
#pragma unroll
    for (int j = 0; j < 8; ++j) {
      __bf16 pr[2] = {a[j], b[j]};
      *(uint32_t*)&Vt[vs * 8 + j][vpi] = *(const uint32_t*)pr;
    }
  };
  auto readKs = [&](int wr, int g) -> b8v {
    int gs = g ^ (wr & 7);
    return *(const b8v*)((const char*)Ks + wr * 128 + gs * 16);
  };

  float mst[5][4], lst[5][4];
  f4 oacc[5][2];
#pragma unroll
  for (int t = 0; t < 5; ++t) {
#pragma unroll
    for (int r = 0; r < 4; ++r) { mst[t][r] = -1e30f; lst[t][r] = 0.f; }
    oacc[t][0] = f4{0.f, 0.f, 0.f, 0.f};
    oacc[t][1] = f4{0.f, 0.f, 0.f, 0.f};
  }

  auto compute = [&]() {
#pragma unroll
    for (int t = 0; t < 5; ++t) {
      // S = Q K^T : 16 q-rows x 128 l-cols
      f4 sc[8];
#pragma unroll
      for (int ct = 0; ct < 8; ++ct) {
        b8v kb0 = readKs(ct * 16 + lrow, quad);
        b8v kb1 = readKs(ct * 16 + lrow, 4 + quad);
        f4 z = f4{0.f, 0.f, 0.f, 0.f};
        z = MFMA_BF16(qa0[t], kb0, z);
        z = MFMA_BF16(qa1[t], kb1, z);
        sc[ct] = z;
      }
      // online softmax (row = quad*4+r; reduce over 16 lanes of the quad)
      float rmax[4], rsum[4], alpha[4];
#pragma unroll
      for (int r = 0; r < 4; ++r) {
        float v = sc[0][r];
#pragma unroll
        for (int ct = 1; ct < 8; ++ct) v = fmaxf(v, sc[ct][r]);
        rmax[r] = v;
      }
#pragma unroll
      for (int off = 8; off >= 1; off >>= 1)
#pragma unroll
        for (int r = 0; r < 4; ++r)
          rmax[r] = fmaxf(rmax[r], __shfl_xor(rmax[r], off, 16));
#pragma unroll
      for (int r = 0; r < 4; ++r) {
        float mnew = fmaxf(mst[t][r], rmax[r]);
        alpha[r] = __expf(mst[t][r] - mnew);
        mst[t][r] = mnew;
      }
#pragma unroll
      for (int ct = 0; ct < 8; ++ct)
#pragma unroll
        for (int r = 0; r < 4; ++r)
          sc[ct][r] = __expf(sc[ct][r] - mst[t][r]);
#pragma unroll
      for (int r = 0; r < 4; ++r) {
        float v = sc[0][r];
#pragma unroll
        for (int ct = 1; ct < 8; ++ct) v += sc[ct][r];
        rsum[r] = v;
      }
#pragma unroll
      for (int off = 8; off >= 1; off >>= 1)
#pragma unroll
        for (int r = 0; r < 4; ++r)
          rsum[r] += __shfl_xor(rsum[r], off, 16);
#pragma unroll
      for (int r = 0; r < 4; ++r) lst[t][r] = lst[t][r] * alpha[r] + rsum[r];
#pragma unroll
      for (int c2 = 0; c2 < 2; ++c2)
#pragma unroll
        for (int r = 0; r < 4; ++r) oacc[t][c2][r] *= alpha[r];

      // P -> per-wave LDS (A-layout via pi); b128 stores, wave-private (no barrier)
#pragma unroll
      for (int r = 0; r < 4; ++r) {
        b8v pv;
#pragma unroll
        for (int ct = 0; ct < 8; ++ct) pv[ct] = (__bf16)sc[ct][r];
        *(b8v*)&Ps[wave][quad * 4 + r][lrow * 8] = pv;
      }
      // O += P V
#pragma unroll
      for (int kt = 0; kt < 4; ++kt) {
        b8v pa = *(const b8v*)&Ps[wave][lrow][kt * 32 + quad * 8];
#pragma unroll
        for (int c2 = 0; c2 < 2; ++c2) {
          b8v vb = *(const b8v*)&Vt[c2 * 16 + lrow][kt * 32 + quad * 8];
          oacc[t][c2] = MFMA_BF16(pa, vb, oacc[t][c2]);
        }
      }
    }
  };

  uint4 kA[4], vA[2], kB[4], vB[2];
  loadKV(kA, vA, 0);
  for (int c = 0; c < 8; c += 2) {
    __syncthreads();                 // all waves done reading chunk c-1 LDS
    stage(kA, vA);                   // (waits vmcnt on kA/vA regs only)
    loadKV(kB, vB, c + 1);           // prefetch c+1, in flight across compute
    __syncthreads();
    compute();
    __syncthreads();
    stage(kB, vB);
    if (c + 2 < 8) loadKV(kA, vA, c + 2);
    __syncthreads();
    compute();
  }

  // epilogue: normalized partial O (bf16) + m,l (f32)
  const size_t pbase = ((size_t)bh * 4 + ls) * 320;
#pragma unroll
  for (int t = 0; t < 5; ++t) {
#pragma unroll
    for (int r = 0; r < 4; ++r) {
      int q = wave * 80 + t * 16 + quad * 4 + r;
      float inv = 1.0f / lst[t][r];
#pragma unroll
      for (int c2 = 0; c2 < 2; ++c2)
        Opart[(pbase + q) * 32 + c2 * 16 + lrow] = (__bf16)(oacc[t][c2][r] * inv);
      if (lrow == 0) {
        Mpart[pbase + q] = mst[t][r];
        Lpart[pbase + q] = lst[t][r];
      }
    }
  }
}

// ---------------------------------------------------------------------------
// Kernel C2: combine 4 L-split partials -> Obf[b][n][256].
__global__ __launch_bounds__(256) void attn_combine(
    const __bf16* __restrict__ Opart, const float* __restrict__ Mpart,
    const float* __restrict__ Lpart, __bf16* __restrict__ Obf)
{
  const int bh = blockIdx.y;
  const int idx = blockIdx.x * 256 + threadIdx.x;   // 0..10239
  const int q = idx >> 5, d = idx & 31;
  if (q >= 300) return;
  const size_t rb = ((size_t)bh * 4) * 320 + q;
  float m0 = Mpart[rb], m1 = Mpart[rb + 320], m2 = Mpart[rb + 640], m3 = Mpart[rb + 960];
  float M = fmaxf(fmaxf(m0, m1), fmaxf(m2, m3));
  float w0 = Lpart[rb]       * __expf(m0 - M);
  float w1 = Lpart[rb + 320] * __expf(m1 - M);
  float w2 = Lpart[rb + 640] * __expf(m2 - M);
  float w3 = Lpart[rb + 960] * __expf(m3 - M);
  float S = w0 + w1 + w2 + w3;
  float o = w0 * (float)Opart[rb * 32 + d]
          + w1 * (float)Opart[(rb + 320) * 32 + d]
          + w2 * (float)Opart[(rb + 640) * 32 + d]
          + w3 * (float)Opart[(rb + 960) * 32 + d];
  int b = bh >> 3, h = bh & 7;
  Obf[((size_t)b * 300 + q) * 256 + h * 32 + d] = (__bf16)(o / S);
}

// ---------------------------------------------------------------------------
// Kernel D: out = identity + Obf @ W_o^T + b_o (unchanged from R2).
__global__ __launch_bounds__(256) void out_proj_gemm(
    const __bf16* __restrict__ Obf, const float* __restrict__ W_o,
    const float* __restrict__ b_o, const float* __restrict__ query,
    float* __restrict__ out)
{
  __shared__ __bf16 Ws[256][72];
  const int tid  = threadIdx.x;
  const int wave = tid >> 6, lane = tid & 63;
  const int lrow = lane & 15, quad = lane >> 4;
  const int r0 = blockIdx.x * 64;

  f4 acc[16];
#pragma unroll
  for (int i = 0; i < 16; ++i) acc[i] = f4{0.f, 0.f, 0.f, 0.f};

  for (int kc0 = 0; kc0 < 256; kc0 += 64) {
#pragma unroll
    for (int it = 0; it < 16; ++it) {
      int idx = it * 256 + tid;
      int row = idx >> 4, c4 = idx & 15;
      float4 w = *(const float4*)(W_o + (size_t)row * 256 + kc0 + c4 * 4);
      __bf16* dp = &Ws[row][c4 * 4];
      dp[0] = (__bf16)w.x; dp[1] = (__bf16)w.y; dp[2] = (__bf16)w.z; dp[3] = (__bf16)w.w;
    }
    __syncthreads();
#pragma unroll
    for (int kk = 0; kk < 64; kk += 32) {
      b8v a = *(const b8v*)(Obf + (size_t)(r0 + wave * 16 + lrow) * 256 + kc0 + kk + quad * 8);
#pragma unroll
      for (int ct = 0; ct < 16; ++ct) {
        b8v bf = *(const b8v*)&Ws[ct * 16 + lrow][kk + quad * 8];
        acc[ct] = MFMA_BF16(a, bf, acc[ct]);
      }
    }
    __syncthreads();
  }
#pragma unroll
  for (int ct = 0; ct < 16; ++ct) {
    int col = ct * 16 + lrow;
    float bo = b_o[col];
#pragma unroll
    for (int r = 0; r < 4; ++r) {
      int row = r0 + wave * 16 + quad * 4 + r;
      int bb = row / 300, n = row % 300;
      size_t oaddr = ((size_t)n * 16 + bb) * 256 + col;
      out[oaddr] = acc[ct][r] + bo + query[oaddr];
    }
  }
}

// ---------------------------------------------------------------------------
extern "C" void kernel_launch(void* const* d_in, const int* in_sizes, int n_in,
                              void* d_out, int out_size, void* d_ws, size_t ws_size,
                              hipStream_t stream) {
  (void)in_sizes; (void)n_in; (void)out_size; (void)ws_size;
  const float* query      = (const float*)d_in[0];
  const float* key        = (const float*)d_in[1];
  const float* value      = (const float*)d_in[2];
  const float* query_pos  = (const float*)d_in[3];
  const float* key_pos    = (const float*)d_in[4];
  const float* query_sine = (const float*)d_in[5];
  const float* W_qc = (const float*)d_in[6];  const float* b_qc = (const float*)d_in[7];
  const float* W_qp = (const float*)d_in[8];  const float* b_qp = (const float*)d_in[9];
  const float* W_qs = (const float*)d_in[10]; const float* b_qs = (const float*)d_in[11];
  const float* W_kc = (const float*)d_in[12]; const float* b_kc = (const float*)d_in[13];
  const float* W_kp = (const float*)d_in[14]; const float* b_kp = (const float*)d_in[15];
  const float* W_v  = (const float*)d_in[16]; const float* b_v  = (const float*)d_in[17];
  const float* W_o  = (const float*)d_in[18]; const float* b_o  = (const float*)d_in[19];
  float* out = (float*)d_out;

  char* ws = (char*)d_ws;
  constexpr size_t K64_BYTES = (size_t)128 * 4096 * 64 * 2;  // 64 MiB
  constexpr size_t V32_BYTES = (size_t)128 * 4096 * 32 * 2;  // 32 MiB
  constexpr size_t Q64_BYTES = (size_t)128 * 320 * 64 * 2;   //  5 MiB
  constexpr size_t OBF_BYTES = (size_t)16 * 300 * 256 * 2;   //  2.34 MiB
  constexpr size_t WBF_BYTES = (size_t)3 * 256 * 256 * 2;    //  0.375 MiB
  constexpr size_t OPART_BYTES = (size_t)128 * 4 * 320 * 32 * 2;  // 10.49 MB
  constexpr size_t MPART_BYTES = (size_t)128 * 4 * 320 * 4;       // 0.655 MB
  __bf16* K64 = (__bf16*)ws;
  __bf16* V32 = (__bf16*)(ws + K64_BYTES);
  __bf16* Q64 = (__bf16*)(ws + K64_BYTES + V32_BYTES);
  __bf16* Obf = (__bf16*)(ws + K64_BYTES + V32_BYTES + Q64_BYTES);
  __bf16* Wbf = (__bf16*)(ws + K64_BYTES + V32_BYTES + Q64_BYTES + OBF_BYTES);
  char*  pbase = ws + K64_BYTES + V32_BYTES + Q64_BYTES + OBF_BYTES + WBF_BYTES;
  __bf16* Opart = (__bf16*)pbase;
  float*  Mpart = (float*)(pbase + OPART_BYTES);
  float*  Lpart = (float*)(pbase + OPART_BYTES + MPART_BYTES);

  hipLaunchKernelGGL(convert_w, dim3(192), dim3(256), 0, stream,
                     W_kc, W_kp, W_v, Wbf);
  hipLaunchKernelGGL(key_side_gemm, dim3(512, 3), dim3(256), 0, stream,
                     key, key_pos, value, Wbf, b_kc, b_kp, b_v, K64, V32);
  hipLaunchKernelGGL(query_side_gemm, dim3(75), dim3(256), 0, stream,
                     query, query_pos, query_sine, W_qc, b_qc, W_qp, b_qp, W_qs, b_qs, Q64);
  hipLaunchKernelGGL(attn_part, dim3(4, 128), dim3(256), 0, stream,
                     Q64, K64, V32, Opart, Mpart, Lpart);
  hipLaunchKernelGGL(attn_combine, dim3(40, 128), dim3(256), 0, stream,
                     Opart, Mpart, Lpart, Obf);
  hipLaunchKernelGGL(out_proj_gemm, dim3(75), dim3(256), 0, stream,
                     Obf, W_o, b_o, query, out);
}

// Round 4
// 459.593 us; speedup vs baseline: 1.1202x; 1.1202x over previous
//
#include <hip/hip_runtime.h>
#include <cstdint>
#include <cstddef>

// MI355X / gfx950. bf16 MFMA implementation of ConditionalCrossAttention.
// score = (qc+qp)|(qc+qp+qs)  dot  kc|kp   (algebraic refold of the concat heads)
// attn v4: S^T orientation (q = lane&15) -> softmax mostly in-lane, scalar m/l
// per lane, natural-layout P^T/V^T LDS tiles, no spills.

typedef float  f4  __attribute__((ext_vector_type(4)));
typedef __bf16 b8v __attribute__((ext_vector_type(8)));

#define MFMA_BF16(a, b, c) __builtin_amdgcn_mfma_f32_16x16x32_bf16((a), (b), (c), 0, 0, 0)

#define GLD_LDS16(gp, lp)                                             \
  __builtin_amdgcn_global_load_lds(                                   \
      (const __attribute__((address_space(1))) void*)(gp),            \
      (__attribute__((address_space(3))) void*)(lp), 16, 0, 0)

// ---------------------------------------------------------------------------
// Prepass: convert key-side weights fp32 -> bf16 (W_kc, W_kp, W_v -> Wbf[3][256*256])
__global__ __launch_bounds__(256) void convert_w(
    const float* __restrict__ W0, const float* __restrict__ W1,
    const float* __restrict__ W2, __bf16* __restrict__ Wbf)
{
  int i = blockIdx.x * 256 + threadIdx.x;      // 0 .. 49151
  int base = i * 4;                            // elem index, 4 per thread
  int m = base >> 16;                          // which matrix
  int off = base & 65535;
  const float* W = (m == 0) ? W0 : (m == 1) ? W1 : W2;
  float4 v = *(const float4*)(W + off);
  __bf16 o[4];
  o[0] = (__bf16)v.x; o[1] = (__bf16)v.y; o[2] = (__bf16)v.z; o[3] = (__bf16)v.w;
  *(uint2*)(Wbf + (size_t)m * 65536 + off) = *(uint2*)o;
}

// ---------------------------------------------------------------------------
// Kernel A: key-side linears, m97-style (unchanged from R2/R3).
__global__ __launch_bounds__(256, 2) void key_side_gemm(
    const float* __restrict__ key, const float* __restrict__ key_pos,
    const float* __restrict__ value, const __bf16* __restrict__ Wbf,
    const float* __restrict__ b_kc, const float* __restrict__ b_kp,
    const float* __restrict__ b_v,
    __bf16* __restrict__ K64, __bf16* __restrict__ V32)
{
  __shared__ char smem[65536];   // 2 x 32KB W dbuf; reused as 64KB output tile
  const int tid  = threadIdx.x;
  const int wave = tid >> 6, lane = tid & 63;
  const int lrow = lane & 15, quad = lane >> 4;
  const int p  = blockIdx.y;
  const int r0 = blockIdx.x * 128;
  const int rowbase = (wave & 1) * 64;     // 2x2 wave grid: 64 rows x 128 cols each
  const int colbase = (wave >> 1) * 128;

  const float* __restrict__ X = (p == 0) ? key : (p == 1) ? key_pos : value;
  const __bf16* __restrict__ Wb = Wbf + (size_t)p * 65536;
  const float* __restrict__ bias = (p == 0) ? b_kc : (p == 1) ? b_kp : b_v;

  auto stageW = [&](int buf, int kc) {
#pragma unroll
    for (int it = 0; it < 8; ++it) {
      int slot = it * 256 + tid;            // 2048 granules of 16B
      int wr = slot >> 3, gp = slot & 7;
      int g  = gp ^ (wr & 7);
      GLD_LDS16(Wb + (size_t)wr * 256 + kc + g * 8, smem + buf * 32768 + slot * 16);
    }
  };
  auto readB = [&](int buf, int ct, int kk4) -> b8v {   // kk4 = kk/8 (0 or 4)
    int wr = colbase + ct * 16 + lrow;
    int g  = (kk4 + quad) ^ (wr & 7);
    return *(const b8v*)(smem + buf * 32768 + wr * 128 + g * 16);
  };
  auto loadA = [&](float4* x0, float4* x1, int kc) {
#pragma unroll
    for (int rt = 0; rt < 4; ++rt) {
      const float* xp = X + (size_t)(r0 + rowbase + rt * 16 + lrow) * 256 + kc + quad * 8;
      x0[rt] = *(const float4*)xp;
      x1[rt] = *(const float4*)(xp + 4);
    }
  };
  auto mk = [&](float4 x0, float4 x1) -> b8v {
    b8v t;
    t[0] = (__bf16)x0.x; t[1] = (__bf16)x0.y; t[2] = (__bf16)x0.z; t[3] = (__bf16)x0.w;
    t[4] = (__bf16)x1.x; t[5] = (__bf16)x1.y; t[6] = (__bf16)x1.z; t[7] = (__bf16)x1.w;
    return t;
  };

  f4 acc[4][8];
#pragma unroll
  for (int i = 0; i < 4; ++i)
#pragma unroll
    for (int j = 0; j < 8; ++j) acc[i][j] = f4{0.f, 0.f, 0.f, 0.f};

  float4 c0[4], c1[4], d0[4], d1[4];
  loadA(c0, c1, 0);
  stageW(0, 0);
  __syncthreads();

  for (int s = 0; s < 4; ++s) {
    const int kc0 = s * 64, buf = s & 1;
    loadA(d0, d1, kc0 + 32);
    if (s < 3) stageW(buf ^ 1, kc0 + 64);

    b8v a[4];
#pragma unroll
    for (int rt = 0; rt < 4; ++rt) a[rt] = mk(c0[rt], c1[rt]);
#pragma unroll
    for (int ct = 0; ct < 8; ++ct) {
      b8v bfr = readB(buf, ct, 0);
#pragma unroll
      for (int rt = 0; rt < 4; ++rt) acc[rt][ct] = MFMA_BF16(a[rt], bfr, acc[rt][ct]);
    }

    if (s < 3) loadA(c0, c1, kc0 + 64);

#pragma unroll
    for (int rt = 0; rt < 4; ++rt) a[rt] = mk(d0[rt], d1[rt]);
#pragma unroll
    for (int ct = 0; ct < 8; ++ct) {
      b8v bfr = readB(buf, ct, 4);
#pragma unroll
      for (int rt = 0; rt < 4; ++rt) acc[rt][ct] = MFMA_BF16(a[rt], bfr, acc[rt][ct]);
    }
    __syncthreads();
  }

  // epilogue: acc -> LDS [128][256] bf16 -> coalesced 64B-line stores
  __bf16* Os = (__bf16*)smem;
#pragma unroll
  for (int ct = 0; ct < 8; ++ct) {
    int col = colbase + ct * 16 + lrow;
    float bv = bias[col];
#pragma unroll
    for (int rt = 0; rt < 4; ++rt)
#pragma unroll
      for (int r = 0; r < 4; ++r) {
        int row = rowbase + rt * 16 + quad * 4 + r;
        Os[row * 256 + col] = (__bf16)(acc[rt][ct][r] + bv);
      }
  }
  __syncthreads();
#pragma unroll
  for (int it = 0; it < 16; ++it) {
    int chunk = it * 64 + wave * 16 + (lane & 15);
    int q = lane >> 4;
    int row = chunk >> 3, h = chunk & 7;
    int R = r0 + row, l = R >> 4, bb = R & 15;
    uint4 v = *(const uint4*)(Os + chunk * 32 + q * 8);
    __bf16* dst = (p == 2) ? (V32 + ((size_t)(bb * 8 + h) * 4096 + l) * 32)
                           : (K64 + ((size_t)(bb * 8 + h) * 4096 + l) * 64 + p * 32);
    *(uint4*)(dst + q * 8) = v;
  }
}

// ---------------------------------------------------------------------------
// Kernel B: query-side (unchanged).
__global__ __launch_bounds__(256) void query_side_gemm(
    const float* __restrict__ query, const float* __restrict__ query_pos,
    const float* __restrict__ query_sine,
    const float* __restrict__ W_qc, const float* __restrict__ b_qc,
    const float* __restrict__ W_qp, const float* __restrict__ b_qp,
    const float* __restrict__ W_qs, const float* __restrict__ b_qs,
    __bf16* __restrict__ Q64)
{
  __shared__ __bf16 Ws[256][72];
  const int tid  = threadIdx.x;
  const int wave = tid >> 6, lane = tid & 63;
  const int lrow = lane & 15, quad = lane >> 4;
  const int r0 = blockIdx.x * 64;

  f4 acc[16];
#pragma unroll
  for (int i = 0; i < 16; ++i) acc[i] = f4{0.f, 0.f, 0.f, 0.f};

  for (int kc = 0; kc < 768; kc += 64) {
    const float* X; const float* W;
    if (kc < 256)      { X = query;      W = W_qc; }
    else if (kc < 512) { X = query_pos;  W = W_qp; }
    else               { X = query_sine; W = W_qs; }
    const int ko = kc & 255;
#pragma unroll
    for (int it = 0; it < 16; ++it) {
      int idx = it * 256 + tid;
      int row = idx >> 4, c4 = idx & 15;
      float4 w = *(const float4*)(W + (size_t)row * 256 + ko + c4 * 4);
      __bf16* dp = &Ws[row][c4 * 4];
      dp[0] = (__bf16)w.x; dp[1] = (__bf16)w.y; dp[2] = (__bf16)w.z; dp[3] = (__bf16)w.w;
    }
    __syncthreads();
#pragma unroll
    for (int kk = 0; kk < 64; kk += 32) {
      const float* xp = X + (size_t)(r0 + wave * 16 + lrow) * 256 + ko + kk + quad * 8;
      float4 x0 = *(const float4*)xp;
      float4 x1 = *(const float4*)(xp + 4);
      b8v a;
      a[0] = (__bf16)x0.x; a[1] = (__bf16)x0.y; a[2] = (__bf16)x0.z; a[3] = (__bf16)x0.w;
      a[4] = (__bf16)x1.x; a[5] = (__bf16)x1.y; a[6] = (__bf16)x1.z; a[7] = (__bf16)x1.w;
#pragma unroll
      for (int ct = 0; ct < 16; ++ct) {
        b8v bf = *(const b8v*)&Ws[ct * 16 + lrow][kk + quad * 8];
        acc[ct] = MFMA_BF16(a, bf, acc[ct]);
      }
    }
    __syncthreads();
    if (kc == 448) {
#pragma unroll
      for (int ct = 0; ct < 16; ++ct) {
        int col = ct * 16 + lrow;
        float bsum = b_qc[col] + b_qp[col];
        int h = col >> 5, d = col & 31;
#pragma unroll
        for (int r = 0; r < 4; ++r) {
          int row = r0 + wave * 16 + quad * 4 + r;
          int n = row >> 4, bb = row & 15;
          Q64[((size_t)(bb * 8 + h) * 320 + n) * 64 + d] = (__bf16)((acc[ct][r] + bsum) * 0.125f);
        }
      }
    }
  }
#pragma unroll
  for (int ct = 0; ct < 16; ++ct) {
    int col = ct * 16 + lrow;
    float bsum = b_qc[col] + b_qp[col] + b_qs[col];
    int h = col >> 5, d = col & 31;
#pragma unroll
    for (int r = 0; r < 4; ++r) {
      int row = r0 + wave * 16 + quad * 4 + r;
      int n = row >> 4, bb = row & 15;
      Q64[((size_t)(bb * 8 + h) * 320 + n) * 64 + 32 + d] = (__bf16)((acc[ct][r] + bsum) * 0.125f);
    }
  }
}

// ---------------------------------------------------------------------------
// Kernel C v4: flash attention, L-split, S^T orientation.
// Grid (4 L-splits, 128 bh), 256 threads. Each wave owns 80 q-rows (5 tiles).
// S^T = MFMA(K_frag, Q_frag): tile row l = ct*16+quad*4+r, col q = lane&15.
//  -> softmax over l = 31-op in-lane tree + 2 shfl_xor; m/l = 1 scalar/lane/tile.
//  -> P^T[q][l] LDS roundtrip with natural layout (b64 writes, b128 reads).
//  -> O^T = MFMA(V^T_frag, P^T_frag); V^T staged natural [d][l] (no pi).
// K/V register-prefetched one chunk ahead; single-buffer LDS between barriers.
__global__ __launch_bounds__(256, 2) void attn_part(
    const __bf16* __restrict__ Q64, const __bf16* __restrict__ K64,
    const __bf16* __restrict__ V32,
    __bf16* __restrict__ Opart, float* __restrict__ Mpart, float* __restrict__ Lpart)
{
  __shared__ __bf16 Ks[128 * 64];     // 16 KB, xor-swizzled 16B granules
  __shared__ __bf16 Vt[32][136];      // 8.5 KB, natural [d][l]
  __shared__ __bf16 Pt[4][16][136];   // 17.4 KB, per-wave P^T [q][l]
  const int tid  = threadIdx.x;
  const int wave = tid >> 6, lane = tid & 63;
  const int lrow = lane & 15, quad = lane >> 4;
  const int ls = blockIdx.x, bh = blockIdx.y;
  const int l0base = ls * 1024;

  const __bf16* Kb = K64 + (size_t)bh * 4096 * 64;
  const __bf16* Vb = V32 + (size_t)bh * 4096 * 32;

  // Q fragments: 5 tiles of 16 q-rows per wave; serves as MFMA B operand.
  b8v qa0[5], qa1[5];
#pragma unroll
  for (int t = 0; t < 5; ++t) {
    const __bf16* Qb = Q64 + ((size_t)bh * 320 + wave * 80 + t * 16 + lrow) * 64;
    qa0[t] = *(const b8v*)(Qb + quad * 8);
    qa1[t] = *(const b8v*)(Qb + 32 + quad * 8);
  }

  // V staging map: thread (vs = d-octet, vrh = l-pair) loads rows 2vrh, 2vrh+1
  const int vs = tid & 3, vrh = tid >> 2;    // vrh 0..63

  auto loadKV = [&](uint4* kr, uint4* vv, int c) {
    int l0 = l0base + c * 128;
#pragma unroll
    for (int it = 0; it < 4; ++it) {
      int slot = it * 256 + tid, row = slot >> 3, gs = slot & 7;
      int g = gs ^ (row & 7);
      kr[it] = *(const uint4*)(Kb + (size_t)(l0 + row) * 64 + g * 8);
    }
    vv[0] = *(const uint4*)(Vb + (size_t)(l0 + 2 * vrh) * 32 + vs * 8);
    vv[1] = *(const uint4*)(Vb + (size_t)(l0 + 2 * vrh + 1) * 32 + vs * 8);
  };
  auto stage = [&](const uint4* kr, const uint4* vv) {
#pragma unroll
    for (int it = 0; it < 4; ++it) {
      int slot = it * 256 + tid;
      *(uint4*)((char*)Ks + slot * 16) = kr[it];
    }
    __bf16 a[8], b[8];
    *(uint4*)a = vv[0]; *(uint4*)b = vv[1];
#pragma unroll
    for (int j = 0; j < 8; ++j) {
      __bf16 pr[2] = {a[j], b[j]};
      *(uint32_t*)&Vt[vs * 8 + j][2 * vrh] = *(const uint32_t*)pr;
    }
  };
  auto readKA = [&](int wr, int g) -> b8v {   // K[l=wr][c = g*8 .. +8]
    int gs = g ^ (wr & 7);
    return *(const b8v*)((const char*)Ks + wr * 128 + gs * 16);
  };

  float mst[5], lst[5];
  f4 oacc[5][2];
#pragma unroll
  for (int t = 0; t < 5; ++t) {
    mst[t] = -1e30f; lst[t] = 0.f;
    oacc[t][0] = f4{0.f, 0.f, 0.f, 0.f};
    oacc[t][1] = f4{0.f, 0.f, 0.f, 0.f};
  }

  auto compute = [&]() {
#pragma unroll
    for (int t = 0; t < 5; ++t) {
      // S^T tiles: row l = ct*16 + quad*4 + r, col q = lrow
      f4 sc[8];
#pragma unroll
      for (int ct = 0; ct < 8; ++ct) {
        b8v ka0 = readKA(ct * 16 + lrow, quad);
        b8v ka1 = readKA(ct * 16 + lrow, 4 + quad);
        f4 z = f4{0.f, 0.f, 0.f, 0.f};
        z = MFMA_BF16(ka0, qa0[t], z);
        z = MFMA_BF16(ka1, qa1[t], z);
        sc[ct] = z;
      }
      // softmax over l: in-lane (32 vals) + cross-quad (lane^16, lane^32)
      float mx = sc[0][0];
#pragma unroll
      for (int ct = 0; ct < 8; ++ct)
#pragma unroll
        for (int r = 0; r < 4; ++r) mx = fmaxf(mx, sc[ct][r]);
      mx = fmaxf(mx, __shfl_xor(mx, 16));
      mx = fmaxf(mx, __shfl_xor(mx, 32));
      float mnew = fmaxf(mst[t], mx);
      float alpha = __expf(mst[t] - mnew);
      mst[t] = mnew;
      float rsum = 0.f;
#pragma unroll
      for (int ct = 0; ct < 8; ++ct)
#pragma unroll
        for (int r = 0; r < 4; ++r) {
          sc[ct][r] = __expf(sc[ct][r] - mnew);
          rsum += sc[ct][r];
        }
      rsum += __shfl_xor(rsum, 16);
      rsum += __shfl_xor(rsum, 32);
      lst[t] = lst[t] * alpha + rsum;
#pragma unroll
      for (int c2 = 0; c2 < 2; ++c2)
#pragma unroll
        for (int r = 0; r < 4; ++r) oacc[t][c2][r] *= alpha;

      // P^T -> per-wave LDS [q=lrow][l]; b64 writes (4 consecutive l per reg)
#pragma unroll
      for (int ct = 0; ct < 8; ++ct) {
        __bf16 p4[4];
#pragma unroll
        for (int r = 0; r < 4; ++r) p4[r] = (__bf16)sc[ct][r];
        *(uint2*)&Pt[wave][lrow][ct * 16 + quad * 4] = *(const uint2*)p4;
      }
      // O^T += V^T P^T
#pragma unroll
      for (int kt = 0; kt < 4; ++kt) {
        b8v pb = *(const b8v*)&Pt[wave][lrow][kt * 32 + quad * 8];
#pragma unroll
        for (int c2 = 0; c2 < 2; ++c2) {
          b8v va = *(const b8v*)&Vt[c2 * 16 + lrow][kt * 32 + quad * 8];
          oacc[t][c2] = MFMA_BF16(va, pb, oacc[t][c2]);
        }
      }
    }
  };

  uint4 kA[4], vA[2], kB[4], vB[2];
  loadKV(kA, vA, 0);
  for (int c = 0; c < 8; c += 2) {
    __syncthreads();
    stage(kA, vA);
    loadKV(kB, vB, c + 1);           // prefetch, in flight across compute
    __syncthreads();
    compute();
    __syncthreads();
    stage(kB, vB);
    if (c + 2 < 8) loadKV(kA, vA, c + 2);
    __syncthreads();
    compute();
  }

  // epilogue: O^T[d][q] -> Opart[q][d] (b64 packed), m/l per q
  const size_t pbase = ((size_t)bh * 4 + ls) * 320;
#pragma unroll
  for (int t = 0; t < 5; ++t) {
    int q = wave * 80 + t * 16 + lrow;
    float inv = 1.0f / lst[t];
#pragma unroll
    for (int c2 = 0; c2 < 2; ++c2) {
      __bf16 o4[4];
#pragma unroll
      for (int r = 0; r < 4; ++r) o4[r] = (__bf16)(oacc[t][c2][r] * inv);
      *(uint2*)&Opart[(pbase + q) * 32 + c2 * 16 + quad * 4] = *(const uint2*)o4;
    }
    if (quad == 0) {
      Mpart[pbase + q] = mst[t];
      Lpart[pbase + q] = lst[t];
    }
  }
}

// ---------------------------------------------------------------------------
// Kernel C2: combine 4 L-split partials -> Obf[b][n][256] (unchanged).
__global__ __launch_bounds__(256) void attn_combine(
    const __bf16* __restrict__ Opart, const float* __restrict__ Mpart,
    const float* __restrict__ Lpart, __bf16* __restrict__ Obf)
{
  const int bh = blockIdx.y;
  const int idx = blockIdx.x * 256 + threadIdx.x;   // 0..10239
  const int q = idx >> 5, d = idx & 31;
  if (q >= 300) return;
  const size_t rb = ((size_t)bh * 4) * 320 + q;
  float m0 = Mpart[rb], m1 = Mpart[rb + 320], m2 = Mpart[rb + 640], m3 = Mpart[rb + 960];
  float M = fmaxf(fmaxf(m0, m1), fmaxf(m2, m3));
  float w0 = Lpart[rb]       * __expf(m0 - M);
  float w1 = Lpart[rb + 320] * __expf(m1 - M);
  float w2 = Lpart[rb + 640] * __expf(m2 - M);
  float w3 = Lpart[rb + 960] * __expf(m3 - M);
  float S = w0 + w1 + w2 + w3;
  float o = w0 * (float)Opart[rb * 32 + d]
          + w1 * (float)Opart[(rb + 320) * 32 + d]
          + w2 * (float)Opart[(rb + 640) * 32 + d]
          + w3 * (float)Opart[(rb + 960) * 32 + d];
  int b = bh >> 3, h = bh & 7;
  Obf[((size_t)b * 300 + q) * 256 + h * 32 + d] = (__bf16)(o / S);
}

// ---------------------------------------------------------------------------
// Kernel D: out = identity + Obf @ W_o^T + b_o (unchanged).
__global__ __launch_bounds__(256) void out_proj_gemm(
    const __bf16* __restrict__ Obf, const float* __restrict__ W_o,
    const float* __restrict__ b_o, const float* __restrict__ query,
    float* __restrict__ out)
{
  __shared__ __bf16 Ws[256][72];
  const int tid  = threadIdx.x;
  const int wave = tid >> 6, lane = tid & 63;
  const int lrow = lane & 15, quad = lane >> 4;
  const int r0 = blockIdx.x * 64;

  f4 acc[16];
#pragma unroll
  for (int i = 0; i < 16; ++i) acc[i] = f4{0.f, 0.f, 0.f, 0.f};

  for (int kc0 = 0; kc0 < 256; kc0 += 64) {
#pragma unroll
    for (int it = 0; it < 16; ++it) {
      int idx = it * 256 + tid;
      int row = idx >> 4, c4 = idx & 15;
      float4 w = *(const float4*)(W_o + (size_t)row * 256 + kc0 + c4 * 4);
      __bf16* dp = &Ws[row][c4 * 4];
      dp[0] = (__bf16)w.x; dp[1] = (__bf16)w.y; dp[2] = (__bf16)w.z; dp[3] = (__bf16)w.w;
    }
    __syncthreads();
#pragma unroll
    for (int kk = 0; kk < 64; kk += 32) {
      b8v a = *(const b8v*)(Obf + (size_t)(r0 + wave * 16 + lrow) * 256 + kc0 + kk + quad * 8);
#pragma unroll
      for (int ct = 0; ct < 16; ++ct) {
        b8v bf = *(const b8v*)&Ws[ct * 16 + lrow][kk + quad * 8];
        acc[ct] = MFMA_BF16(a, bf, acc[ct]);
      }
    }
    __syncthreads();
  }
#pragma unroll
  for (int ct = 0; ct < 16; ++ct) {
    int col = ct * 16 + lrow;
    float bo = b_o[col];
#pragma unroll
    for (int r = 0; r < 4; ++r) {
      int row = r0 + wave * 16 + quad * 4 + r;
      int bb = row / 300, n = row % 300;
      size_t oaddr = ((size_t)n * 16 + bb) * 256 + col;
      out[oaddr] = acc[ct][r] + bo + query[oaddr];
    }
  }
}

// ---------------------------------------------------------------------------
extern "C" void kernel_launch(void* const* d_in, const int* in_sizes, int n_in,
                              void* d_out, int out_size, void* d_ws, size_t ws_size,
                              hipStream_t stream) {
  (void)in_sizes; (void)n_in; (void)out_size; (void)ws_size;
  const float* query      = (const float*)d_in[0];
  const float* key        = (const float*)d_in[1];
  const float* value      = (const float*)d_in[2];
  const float* query_pos  = (const float*)d_in[3];
  const float* key_pos    = (const float*)d_in[4];
  const float* query_sine = (const float*)d_in[5];
  const float* W_qc = (const float*)d_in[6];  const float* b_qc = (const float*)d_in[7];
  const float* W_qp = (const float*)d_in[8];  const float* b_qp = (const float*)d_in[9];
  const float* W_qs = (const float*)d_in[10]; const float* b_qs = (const float*)d_in[11];
  const float* W_kc = (const float*)d_in[12]; const float* b_kc = (const float*)d_in[13];
  const float* W_kp = (const float*)d_in[14]; const float* b_kp = (const float*)d_in[15];
  const float* W_v  = (const float*)d_in[16]; const float* b_v  = (const float*)d_in[17];
  const float* W_o  = (const float*)d_in[18]; const float* b_o  = (const float*)d_in[19];
  float* out = (float*)d_out;

  char* ws = (char*)d_ws;
  constexpr size_t K64_BYTES = (size_t)128 * 4096 * 64 * 2;  // 64 MiB
  constexpr size_t V32_BYTES = (size_t)128 * 4096 * 32 * 2;  // 32 MiB
  constexpr size_t Q64_BYTES = (size_t)128 * 320 * 64 * 2;   //  5 MiB
  constexpr size_t OBF_BYTES = (size_t)16 * 300 * 256 * 2;   //  2.34 MiB
  constexpr size_t WBF_BYTES = (size_t)3 * 256 * 256 * 2;    //  0.375 MiB
  constexpr size_t OPART_BYTES = (size_t)128 * 4 * 320 * 32 * 2;  // 10.49 MB
  constexpr size_t MPART_BYTES = (size_t)128 * 4 * 320 * 4;       // 0.655 MB
  __bf16* K64 = (__bf16*)ws;
  __bf16* V32 = (__bf16*)(ws + K64_BYTES);
  __bf16* Q64 = (__bf16*)(ws + K64_BYTES + V32_BYTES);
  __bf16* Obf = (__bf16*)(ws + K64_BYTES + V32_BYTES + Q64_BYTES);
  __bf16* Wbf = (__bf16*)(ws + K64_BYTES + V32_BYTES + Q64_BYTES + OBF_BYTES);
  char*  pbase = ws + K64_BYTES + V32_BYTES + Q64_BYTES + OBF_BYTES + WBF_BYTES;
  __bf16* Opart = (__bf16*)pbase;
  float*  Mpart = (float*)(pbase + OPART_BYTES);
  float*  Lpart = (float*)(pbase + OPART_BYTES + MPART_BYTES);

  hipLaunchKernelGGL(convert_w, dim3(192), dim3(256), 0, stream,
                     W_kc, W_kp, W_v, Wbf);
  hipLaunchKernelGGL(key_side_gemm, dim3(512, 3), dim3(256), 0, stream,
                     key, key_pos, value, Wbf, b_kc, b_kp, b_v, K64, V32);
  hipLaunchKernelGGL(query_side_gemm, dim3(75), dim3(256), 0, stream,
                     query, query_pos, query_sine, W_qc, b_qc, W_qp, b_qp, W_qs, b_qs, Q64);
  hipLaunchKernelGGL(attn_part, dim3(4, 128), dim3(256), 0, stream,
                     Q64, K64, V32, Opart, Mpart, Lpart);
  hipLaunchKernelGGL(attn_combine, dim3(40, 128), dim3(256), 0, stream,
                     Opart, Mpart, Lpart, Obf);
  hipLaunchKernelGGL(out_proj_gemm, dim3(75), dim3(256), 0, stream,
                     Obf, W_o, b_o, query, out);
}